// Round 19
// baseline (39.578 us; speedup 1.0000x reference)
//
#include <hip/hip_runtime.h>
#include <hip/hip_bf16.h>

typedef int   v4i __attribute__((ext_vector_type(4)));
typedef float v4f __attribute__((ext_vector_type(4)));

#define HWSZ 3136   // 56*56
#define IMW  56
#define CIN  64
#define COUT 128
#define ROWB 3712   // 58 px * 64 c per LDS window row

__device__ __forceinline__ float step_size(float a) {
    a = a > 0.f ? a : 0.f;              // relu(alpha)
    return 2.0f * a / 254.0f;
}

__device__ __forceinline__ int quant1(float x, float s) {
    float v = rintf(x / s);             // round-half-even like jnp.round
    v = fminf(127.f, fmaxf(-127.f, v)); // clip(-127, 127)
    return (int)v;
}

__device__ __forceinline__ unsigned int pack4(int a, int b, int c, int d) {
    return (unsigned int)(a & 255) | ((unsigned int)(b & 255) << 8) |
           ((unsigned int)(c & 255) << 16) | ((unsigned int)(d & 255) << 24);
}

// ---------------- w quantize: OIHW fp32 -> wt[tap][o][c] int8 ----------------
__global__ __launch_bounds__(256) void quantw_kernel(const float* __restrict__ w,
                                                     const float* __restrict__ alpha_w,
                                                     signed char* __restrict__ wt) {
    float s = step_size(alpha_w[0]);
    int j = blockIdx.x * 256 + threadIdx.x;   // 73728 total
    int tap = j / 8192;
    int r   = j % 8192;
    int o   = r >> 6;
    int c   = r & 63;
    wt[j] = (signed char)quant1(w[((size_t)o * 64 + c) * 9 + tap], s);
}

// ---------------- fused quant+conv ----------------
// block = 256 thr = 4 waves (o-quarters), tile = 64 px x 128 o, grid 1568.
// A-staging: load x fp32 window (5 rows x 56 px x 64 c) coalesced, quantize
// in-register (identical integer codes as before), ds_write packed u32 into
// as_ [r][px][c]; pad rows/cols written as zeros. Tap loop (zero-VMEM, MFMA
// from LDS + breg) and LDS-transpose full-line store epilogue unchanged (R16).
__global__ __launch_bounds__(256, 4) void conv_kernel(const float* __restrict__ x,
                                                      const signed char* __restrict__ wt,
                                                      const float* __restrict__ ax,
                                                      const float* __restrict__ aw,
                                                      float* __restrict__ out) {
    __shared__ __attribute__((aligned(16))) signed char as_[34816]; // window 18560 | scratch 4*8704
    float sx    = step_size(ax[0]);
    float scale = sx * step_size(aw[0]);
    int tid  = threadIdx.x;
    int lane = tid & 63;
    int wid  = tid >> 6;    // 0..3: o-quarter
    int row  = lane & 15;
    int kg   = lane >> 4;

    int bid  = blockIdx.x;
    int swz  = (bid & 7) * 196 + (bid >> 3);   // XCD swizzle (x L2 locality)
    int p0   = swz * 64;
    int n    = p0 / HWSZ;
    int hw0  = p0 % HWSZ;
    int h0   = hw0 / IMW;
    int us   = h0 - 1; if (us > 52) us = 52;   // window = unpadded rows us..us+4

    // ---- B preload first: loads in flight while staging does VALU work ----
    int obase = wid * 32;
    const signed char* wb = wt + (obase + row) * 64 + kg * 16;
    v4i breg[9][2];
#pragma unroll
    for (int tap = 0; tap < 9; ++tap)
#pragma unroll
        for (int ot = 0; ot < 2; ++ot)
            breg[tap][ot] = *(const v4i*)(wb + tap * (COUT * 64) + ot * (16 * 64));

    // ---- fused-quant A staging: window row r holds unpadded row u = us+r ----
    {
        int g  = tid & 15;   // px 4-group (0..13 valid)
        int cq = tid >> 4;   // channel quad 0..15
#pragma unroll
        for (int r = 0; r < 5; ++r) {
            int u = us + r;
            signed char* lrow = as_ + r * ROWB;
            if (u < 0 || u > 55) {
                unsigned int* lp = (unsigned int*)lrow;   // 928 dwords
#pragma unroll
                for (int k = 0; k < 4; ++k) {
                    int idx = k * 256 + tid;
                    if (idx < 928) lp[idx] = 0;
                }
            } else {
                if (g < 14) {
                    const float* xb = x + (size_t)(n * CIN + cq * 4) * HWSZ + u * IMW + g * 4;
                    v4f f0 = *(const v4f*)(xb);
                    v4f f1 = *(const v4f*)(xb + HWSZ);
                    v4f f2 = *(const v4f*)(xb + 2 * HWSZ);
                    v4f f3 = *(const v4f*)(xb + 3 * HWSZ);
#pragma unroll
                    for (int j = 0; j < 4; ++j) {
                        unsigned int uq = pack4(quant1(f0[j], sx), quant1(f1[j], sx),
                                                quant1(f2[j], sx), quant1(f3[j], sx));
                        *(unsigned int*)(lrow + (1 + g * 4 + j) * 64 + cq * 4) = uq;
                    }
                } else if (g == 14) {
                    *(unsigned int*)(lrow + cq * 4) = 0;            // px 0 (left pad)
                    *(unsigned int*)(lrow + 57 * 64 + cq * 4) = 0;  // px 57 (right pad)
                }
            }
        }
    }

    // per-lane LDS A base per px tile (window row = hh - us, col = ww+1)
    int lbase[4];
#pragma unroll
    for (int pt = 0; pt < 4; ++pt) {
        int hwp = hw0 + pt * 16 + row;
        int hh  = hwp / IMW, ww = hwp % IMW;
        lbase[pt] = (hh - us) * ROWB + (ww + 1) * 64 + kg * 16;
    }

    __syncthreads();
#pragma unroll
    for (int tap = 0; tap < 9; ++tap)
#pragma unroll
        for (int ot = 0; ot < 2; ++ot)
            asm volatile("" :: "v"(breg[tap][ot]));

    v4i acc[4][2] = {};
#pragma unroll
    for (int tap = 0; tap < 9; ++tap) {
        int doff = (tap / 3 - 1) * ROWB + (tap % 3 - 1) * 64;
        v4i a[4];
#pragma unroll
        for (int pt = 0; pt < 4; ++pt)
            a[pt] = *(const v4i*)(as_ + lbase[pt] + doff);
#pragma unroll
        for (int pt = 0; pt < 4; ++pt)
#pragma unroll
            for (int ot = 0; ot < 2; ++ot)
                acc[pt][ot] = __builtin_amdgcn_mfma_i32_16x16x64_i8(a[pt], breg[tap][ot], acc[pt][ot], 0, 0, 0);
    }

    // ---- LDS-transpose epilogue (full-line 1 KB stores), unchanged ----
    __syncthreads();
    signed char* scrw = as_ + wid * 8704;
    float* obb = out + ((size_t)n * COUT) * HWSZ + hw0;

#pragma unroll
    for (int otl = 0; otl < 2; ++otl) {
        int ol = otl * 16 + row;
#pragma unroll
        for (int pt = 0; pt < 4; ++pt) {
            int c  = pt * 4 + kg;
            int cs = c ^ (ol & 7);
            v4f v;
            v[0] = scale * (float)acc[pt][otl][0];
            v[1] = scale * (float)acc[pt][otl][1];
            v[2] = scale * (float)acc[pt][otl][2];
            v[3] = scale * (float)acc[pt][otl][3];
            *(v4f*)(scrw + ol * 272 + cs * 16) = v;
        }
    }
    {
        int og = lane >> 4;
        int c  = lane & 15;
#pragma unroll
        for (int j = 0; j < 8; ++j) {
            int ol = j * 4 + og;
            int cs = c ^ (ol & 7);
            v4f v = *(const v4f*)(scrw + ol * 272 + cs * 16);
            int o = obase + ol;
            *(v4f*)(obb + (size_t)o * HWSZ + c * 4) = v;
        }
    }
}

extern "C" void kernel_launch(void* const* d_in, const int* in_sizes, int n_in,
                              void* d_out, int out_size, void* d_ws, size_t ws_size,
                              hipStream_t stream) {
    const float* x  = (const float*)d_in[0];
    const float* w  = (const float*)d_in[1];
    const float* ax = (const float*)d_in[2];
    const float* aw = (const float*)d_in[3];
    float* out = (float*)d_out;

    signed char* wt = (signed char*)d_ws;   // 9*128*64 = 73,728 B  [tap][o][c]

    quantw_kernel<<<288, 256, 0, stream>>>(w, aw, wt);
    conv_kernel<<<1568, 256, 0, stream>>>(x, wt, ax, aw, out);
}

// Round 20
// 34.388 us; speedup vs baseline: 1.1509x; 1.1509x over previous
//
#include <hip/hip_runtime.h>
#include <hip/hip_bf16.h>

typedef int   v4i __attribute__((ext_vector_type(4)));
typedef float v4f __attribute__((ext_vector_type(4)));

#define HWSZ 3136   // 56*56
#define IMW  56
#define PADW 58     // 56+2 halo
#define PHW  3364   // 58*58
#define CIN  64
#define COUT 128
#define ROWB 3712   // 58 px * 64 c per LDS window row

__device__ __forceinline__ float step_size(float a) {
    a = a > 0.f ? a : 0.f;              // relu(alpha)
    return 2.0f * a / 254.0f;
}

__device__ __forceinline__ int quant1(float x, float s) {
    float v = rintf(x / s);             // round-half-even like jnp.round
    v = fminf(127.f, fmaxf(-127.f, v)); // clip(-127, 127)
    return (int)v;
}

__device__ __forceinline__ unsigned int pack4(int a, int b, int c, int d) {
    return (unsigned int)(a & 255) | ((unsigned int)(b & 255) << 8) |
           ((unsigned int)(c & 255) << 16) | ((unsigned int)(d & 255) << 24);
}

__device__ __forceinline__ void gload_lds16(const signed char* g, signed char* l) {
    __builtin_amdgcn_global_load_lds(
        (const __attribute__((address_space(1))) void*)g,
        (__attribute__((address_space(3))) void*)l, 16, 0, 0);
}

// ---------------- fused quantize (UNCHANGED from R17) ----------------
__global__ __launch_bounds__(256) void quant_kernel(const float* __restrict__ x,
                                                    const float* __restrict__ w,
                                                    const float* __restrict__ alpha_x,
                                                    const float* __restrict__ alpha_w,
                                                    signed char* __restrict__ cx,
                                                    signed char* __restrict__ wt) {
    int t = threadIdx.x;
    int b = blockIdx.x;
    if (b >= 1568) {
        if (b >= 1856) {
            int q = (b - 1856) * 256 + t;
            int n = q / 912;
            int r = q % 912;
            int px = r >> 2, seg = r & 3;
            int ph, pw;
            if (px < 58)       { ph = 0;  pw = px; }
            else if (px < 116) { ph = 57; pw = px - 58; }
            else { int k = px - 116; ph = 1 + (k >> 1); pw = (k & 1) * 57; }
            v4i z = {0, 0, 0, 0};
            *(v4i*)(cx + ((size_t)n * PHW + ph * PADW + pw) * 64 + seg * 16) = z;
            return;
        }
        float s = step_size(alpha_w[0]);
        int j = (b - 1568) * 256 + t;   // wt flat index in [tap][o][c], 73728 total
        int tap = j / 8192;
        int r   = j % 8192;
        int o   = r >> 6;
        int c   = r & 63;
        float v = w[((size_t)o * 64 + c) * 9 + tap];
        wt[j] = (signed char)quant1(v, s);
        return;
    }

    // x path: one n-slice, one 64-px tile, 64 channels
    __shared__ unsigned int tile32[64 * 17];
    float s = step_size(alpha_x[0]);
    int n   = b / 49;
    int hw0 = (b % 49) * 64;
    int g   = t & 15;
    int cq  = t >> 4;
    int p   = t >> 2;
    int seg = t & 3;

    const float* xb = x + ((size_t)n * CIN + cq * 4) * HWSZ + hw0 + g * 4;
    v4f f0 = *(const v4f*)(xb);
    v4f f1 = *(const v4f*)(xb + HWSZ);
    v4f f2 = *(const v4f*)(xb + 2 * HWSZ);
    v4f f3 = *(const v4f*)(xb + 3 * HWSZ);
#pragma unroll
    for (int j = 0; j < 4; ++j) {
        unsigned int u = pack4(quant1(f0[j], s), quant1(f1[j], s),
                               quant1(f2[j], s), quant1(f3[j], s));
        tile32[(g * 4 + j) * 17 + cq] = u;
    }
    __syncthreads();
    int base = p * 17 + seg * 4;
    v4i val;
    val[0] = (int)tile32[base + 0];
    val[1] = (int)tile32[base + 1];
    val[2] = (int)tile32[base + 2];
    val[3] = (int)tile32[base + 3];
    int hw = hw0 + p;
    int h = hw / IMW, wq = hw % IMW;
    *(v4i*)(cx + ((size_t)n * PHW + (h + 1) * PADW + (wq + 1)) * 64 + seg * 16) = val;
}

// ---------------- conv: 112-px row-aligned tiles ----------------
// tile = 112 px (2 full image rows) x 128 o; block = 256 thr = 4 waves
// (o-quarters), wave = 112 px x 32 o (acc[7][2]). Window = exactly 4 padded
// rows (14,848 B), no clamping. grid = 896 (896%8==0 XCD swizzle).
// Epilogue: 2 rounds x 16 o-rows via LDS scratch -> 448 B runs per o-row.
__global__ __launch_bounds__(256, 3) void conv_kernel(const signed char* __restrict__ cx,
                                                      const signed char* __restrict__ wt,
                                                      const float* __restrict__ ax,
                                                      const float* __restrict__ aw,
                                                      float* __restrict__ out) {
    __shared__ __attribute__((aligned(16))) signed char as_[29184]; // window 16384 | scratch 4*7296
    float scale = step_size(ax[0]) * step_size(aw[0]);
    int tid  = threadIdx.x;
    int lane = tid & 63;
    int wid  = tid >> 6;    // 0..3: o-quarter
    int row  = lane & 15;
    int kg   = lane >> 4;

    int bid = blockIdx.x;
    int swz = (bid & 7) * 112 + (bid >> 3);
    int n   = swz / 28;
    int tl  = swz % 28;
    int hw0 = tl * 112;
    int h0  = tl * 2;          // tile = unpadded rows h0, h0+1
    int us  = h0 - 1;          // window = unpadded us..us+3 = padded h0..h0+3

    // ---- stage window: padded rows h0..h0+3 (14,848 B; 4 rounds, padded to 16 KB) ----
    const signed char* wsrc = cx + ((size_t)n * PHW + (size_t)h0 * PADW) * 64;
#pragma unroll
    for (int r = 0; r < 4; ++r) {
        int slotbase = r * 256 + wid * 64;
        gload_lds16(wsrc + (size_t)(slotbase + lane) * 16, as_ + slotbase * 16);
    }

    // ---- preload B: 9 taps x 2 o-tiles ----
    int obase = wid * 32;
    const signed char* wb = wt + (obase + row) * 64 + kg * 16;
    v4i breg[9][2];
#pragma unroll
    for (int tap = 0; tap < 9; ++tap)
#pragma unroll
        for (int ot = 0; ot < 2; ++ot)
            breg[tap][ot] = *(const v4i*)(wb + tap * (COUT * 64) + ot * (16 * 64));

    // per-lane LDS A base per px tile (7 tiles of 16 px)
    int lbase[7];
#pragma unroll
    for (int pt = 0; pt < 7; ++pt) {
        int hwp = hw0 + pt * 16 + row;
        int hh  = hwp / IMW, ww = hwp % IMW;
        lbase[pt] = (hh - us) * ROWB + (ww + 1) * 64 + kg * 16;
    }

    asm volatile("s_waitcnt vmcnt(0)" ::: "memory");
    __syncthreads();
#pragma unroll
    for (int tap = 0; tap < 9; ++tap)
#pragma unroll
        for (int ot = 0; ot < 2; ++ot)
            asm volatile("" :: "v"(breg[tap][ot]));

    v4i acc[7][2] = {};
#pragma unroll
    for (int tap = 0; tap < 9; ++tap) {
        int doff = (tap / 3 - 1) * ROWB + (tap % 3 - 1) * 64;
        v4i a[7];
#pragma unroll
        for (int pt = 0; pt < 7; ++pt)
            a[pt] = *(const v4i*)(as_ + lbase[pt] + doff);
#pragma unroll
        for (int pt = 0; pt < 7; ++pt)
#pragma unroll
            for (int ot = 0; ot < 2; ++ot)
                acc[pt][ot] = __builtin_amdgcn_mfma_i32_16x16x64_i8(a[pt], breg[tap][ot], acc[pt][ot], 0, 0, 0);
    }

    // ---- epilogue: 2 rounds x 16 o-rows through LDS scratch ----
    __syncthreads();   // window dead; scratch overlays
    signed char* scrw = as_ + wid * 7296;   // 16 o-rows x 456 B
    float* obb = out + ((size_t)n * COUT) * HWSZ + hw0;
    int og = lane >> 5;            // helper for read phase: lane/28 below
    (void)og;

#pragma unroll
    for (int rr = 0; rr < 2; ++rr) {
        // write: 7 ds_write_b128 (px chunk pt*16+kg*4, o-row = row)
#pragma unroll
        for (int pt = 0; pt < 7; ++pt) {
            v4f v;
            v[0] = scale * (float)acc[pt][rr][0];
            v[1] = scale * (float)acc[pt][rr][1];
            v[2] = scale * (float)acc[pt][rr][2];
            v[3] = scale * (float)acc[pt][rr][3];
            *(v4f*)(scrw + row * 456 + pt * 64 + kg * 16) = v;
        }
        // read + store: 8 instrs, each 2 o-rows x 448 B (lanes 0..55)
        if (lane < 56) {
            int g2 = lane / 28;          // 0..1
            int c  = lane - g2 * 28;     // 0..27 px-chunk
#pragma unroll
            for (int j = 0; j < 8; ++j) {
                int ol = j * 2 + g2;     // 0..15
                v4f v = *(const v4f*)(scrw + ol * 456 + c * 16);
                int o = obase + rr * 16 + ol;
                *(v4f*)(obb + (size_t)o * HWSZ + c * 4) = v;
            }
        }
        __builtin_amdgcn_s_waitcnt(0);   // lgkmcnt: reads done before next-round writes (in-wave)
    }
}

extern "C" void kernel_launch(void* const* d_in, const int* in_sizes, int n_in,
                              void* d_out, int out_size, void* d_ws, size_t ws_size,
                              hipStream_t stream) {
    const float* x  = (const float*)d_in[0];
    const float* w  = (const float*)d_in[1];
    const float* ax = (const float*)d_in[2];
    const float* aw = (const float*)d_in[3];
    float* out = (float*)d_out;

    signed char* cx = (signed char*)d_ws;   // 32*3364*64 = 6,889,472 B (padded NHWC)
    signed char* wt = cx + 6889472;         // 9*128*64   =    73,728 B  [tap][o][c]

    quant_kernel<<<1970, 256, 0, stream>>>(x, w, ax, aw, cx, wt);
    conv_kernel<<<896, 256, 0, stream>>>(cx, wt, ax, aw, out);
}

// Round 21
// 32.095 us; speedup vs baseline: 1.2331x; 1.0714x over previous
//
#include <hip/hip_runtime.h>
#include <hip/hip_bf16.h>

typedef int   v4i __attribute__((ext_vector_type(4)));
typedef float v4f __attribute__((ext_vector_type(4)));

#define HWSZ 3136   // 56*56
#define IMW  56
#define PADW 58     // 56+2 halo
#define PHW  3364   // 58*58
#define CIN  64
#define COUT 128
#define ROWB 3712   // 58 px * 64 c per padded LDS window row
#define SROW 1824   // scratch row stride (1792 data + 32 pad, breaks bank alignment)

__device__ __forceinline__ float step_size(float a) {
    a = a > 0.f ? a : 0.f;              // relu(alpha)
    return 2.0f * a / 254.0f;
}

__device__ __forceinline__ int quant1(float x, float s) {
    float v = rintf(x / s);             // round-half-even like jnp.round
    v = fminf(127.f, fmaxf(-127.f, v)); // clip(-127, 127)
    return (int)v;
}

__device__ __forceinline__ unsigned int pack4(int a, int b, int c, int d) {
    return (unsigned int)(a & 255) | ((unsigned int)(b & 255) << 8) |
           ((unsigned int)(c & 255) << 16) | ((unsigned int)(d & 255) << 24);
}

__device__ __forceinline__ void gload_lds16(const signed char* g, signed char* l) {
    __builtin_amdgcn_global_load_lds(
        (const __attribute__((address_space(1))) void*)g,
        (__attribute__((address_space(3))) void*)l, 16, 0, 0);
}

// ---------------- fused quantize (UNCHANGED from R17/R18) ----------------
__global__ __launch_bounds__(256) void quant_kernel(const float* __restrict__ x,
                                                    const float* __restrict__ w,
                                                    const float* __restrict__ alpha_x,
                                                    const float* __restrict__ alpha_w,
                                                    signed char* __restrict__ cx,
                                                    signed char* __restrict__ wt) {
    int t = threadIdx.x;
    int b = blockIdx.x;
    if (b >= 1568) {
        if (b >= 1856) {
            int q = (b - 1856) * 256 + t;
            int n = q / 912;
            int r = q % 912;
            int px = r >> 2, seg = r & 3;
            int ph, pw;
            if (px < 58)       { ph = 0;  pw = px; }
            else if (px < 116) { ph = 57; pw = px - 58; }
            else { int k = px - 116; ph = 1 + (k >> 1); pw = (k & 1) * 57; }
            v4i z = {0, 0, 0, 0};
            *(v4i*)(cx + ((size_t)n * PHW + ph * PADW + pw) * 64 + seg * 16) = z;
            return;
        }
        float s = step_size(alpha_w[0]);
        int j = (b - 1568) * 256 + t;   // wt flat index in [tap][o][c], 73728 total
        int tap = j / 8192;
        int r   = j % 8192;
        int o   = r >> 6;
        int c   = r & 63;
        float v = w[((size_t)o * 64 + c) * 9 + tap];
        wt[j] = (signed char)quant1(v, s);
        return;
    }

    __shared__ unsigned int tile32[64 * 17];
    float s = step_size(alpha_x[0]);
    int n   = b / 49;
    int hw0 = (b % 49) * 64;
    int g   = t & 15;
    int cq  = t >> 4;
    int p   = t >> 2;
    int seg = t & 3;

    const float* xb = x + ((size_t)n * CIN + cq * 4) * HWSZ + hw0 + g * 4;
    v4f f0 = *(const v4f*)(xb);
    v4f f1 = *(const v4f*)(xb + HWSZ);
    v4f f2 = *(const v4f*)(xb + 2 * HWSZ);
    v4f f3 = *(const v4f*)(xb + 3 * HWSZ);
#pragma unroll
    for (int j = 0; j < 4; ++j) {
        unsigned int u = pack4(quant1(f0[j], s), quant1(f1[j], s),
                               quant1(f2[j], s), quant1(f3[j], s));
        tile32[(g * 4 + j) * 17 + cq] = u;
    }
    __syncthreads();
    int base = p * 17 + seg * 4;
    v4i val;
    val[0] = (int)tile32[base + 0];
    val[1] = (int)tile32[base + 1];
    val[2] = (int)tile32[base + 2];
    val[3] = (int)tile32[base + 3];
    int hw = hw0 + p;
    int h = hw / IMW, wq = hw % IMW;
    *(v4i*)(cx + ((size_t)n * PHW + (h + 1) * PADW + (wq + 1)) * 64 + seg * 16) = val;
}

// ---------------- conv: 448-px (8-row) x 32-o blocks ----------------
// block = 256 thr = 4 waves, wave = 112 px x 32 o (acc[7][2], breg[9][2]).
// grid = 224 tiles x 4 o-quarters = 896 (%8==0). Per block: B = 18 KB (vs 72),
// window = exactly 10 padded rows (37,120 B, no clamping), store runs = 1792 B
// per o-row. Epilogue: block-shared scratch (rows padded to 1824 B), fully
// coalesced 1 KB stores, NO vm drains (barriers only).
__global__ __launch_bounds__(256, 3) void conv_kernel(const signed char* __restrict__ cx,
                                                      const signed char* __restrict__ wt,
                                                      const float* __restrict__ ax,
                                                      const float* __restrict__ aw,
                                                      float* __restrict__ out) {
    __shared__ __attribute__((aligned(16))) signed char as_[40960]; // window 37120 | scratch 16*1824 overlay
    float scale = step_size(ax[0]) * step_size(aw[0]);
    int tid  = threadIdx.x;
    int lane = tid & 63;
    int wid  = tid >> 6;    // 0..3: px quarter (112 px each)
    int row  = lane & 15;
    int kg   = lane >> 4;

    int bid  = blockIdx.x;
    int swz  = (bid & 7) * 112 + (bid >> 3);   // XCD-contiguous chunks
    int tile = swz >> 2;    // 0..223
    int oq   = swz & 3;
    int n    = tile / 7;
    int rg   = tile % 7;
    int h0   = rg * 8;      // tile = unpadded rows h0..h0+7
    int px0  = rg * 448;

    // ---- stage window: padded rows h0..h0+9 = 37,120 B = 2320 slots ----
    const signed char* wsrc = cx + ((size_t)n * PHW + (size_t)h0 * PADW) * 64;
#pragma unroll
    for (int r = 0; r < 10; ++r) {
        int slotbase = r * 256 + wid * 64;
        if (slotbase + lane < 2320)
            gload_lds16(wsrc + (size_t)(slotbase + lane) * 16, as_ + slotbase * 16);
    }

    // ---- preload B: this o-quarter only, 9 taps x 2 o-tiles ----
    int ob = oq * 32;
    const signed char* wb = wt + (ob + row) * 64 + kg * 16;
    v4i breg[9][2];
#pragma unroll
    for (int tap = 0; tap < 9; ++tap)
#pragma unroll
        for (int ot = 0; ot < 2; ++ot)
            breg[tap][ot] = *(const v4i*)(wb + tap * (COUT * 64) + ot * (16 * 64));

    // per-lane LDS A base per px tile (7 tiles of 16 px)
    int lbase[7];
#pragma unroll
    for (int pt = 0; pt < 7; ++pt) {
        int px = px0 + wid * 112 + pt * 16 + row;
        int hh = px / IMW, ww = px % IMW;
        lbase[pt] = (hh - h0 + 1) * ROWB + (ww + 1) * 64 + kg * 16;
    }

    asm volatile("s_waitcnt vmcnt(0)" ::: "memory");
    __syncthreads();
#pragma unroll
    for (int tap = 0; tap < 9; ++tap)
#pragma unroll
        for (int ot = 0; ot < 2; ++ot)
            asm volatile("" :: "v"(breg[tap][ot]));

    v4i acc[7][2] = {};
#pragma unroll
    for (int tap = 0; tap < 9; ++tap) {
        int doff = (tap / 3 - 1) * ROWB + (tap % 3 - 1) * 64;
        v4i a[7];
#pragma unroll
        for (int pt = 0; pt < 7; ++pt)
            a[pt] = *(const v4i*)(as_ + lbase[pt] + doff);
#pragma unroll
        for (int pt = 0; pt < 7; ++pt)
#pragma unroll
            for (int ot = 0; ot < 2; ++ot)
                acc[pt][ot] = __builtin_amdgcn_mfma_i32_16x16x64_i8(a[pt], breg[tap][ot], acc[pt][ot], 0, 0, 0);
    }

    // ---- epilogue: 2 rounds x 16 o-rows, block-shared scratch ----
    float* obb = out + ((size_t)n * COUT) * HWSZ + px0;
#pragma unroll
    for (int rr = 0; rr < 2; ++rr) {
        __syncthreads();   // rr=0: window dead; rr=1: prev reads done
        // write: 7 ds_write_b128; scratch[o-local row][px granule]
#pragma unroll
        for (int pt = 0; pt < 7; ++pt) {
            int g = wid * 28 + pt * 4 + kg;   // px quad 0..111
            v4f v;
            v[0] = scale * (float)acc[pt][rr][0];
            v[1] = scale * (float)acc[pt][rr][1];
            v[2] = scale * (float)acc[pt][rr][2];
            v[3] = scale * (float)acc[pt][rr][3];
            *(v4f*)(as_ + row * SROW + g * 16) = v;
        }
        __syncthreads();
        // read + store: each wave 4 o-rows; per row 1792 B (1024 + 768)
#pragma unroll
        for (int r2 = 0; r2 < 4; ++r2) {
            int r4 = wid * 4 + r2;
            int o  = ob + rr * 16 + r4;
            float* orow = obb + (size_t)o * HWSZ;
            v4f v0 = *(const v4f*)(as_ + r4 * SROW + lane * 16);
            *(v4f*)(orow + lane * 4) = v0;
            if (lane < 48) {
                v4f v1 = *(const v4f*)(as_ + r4 * SROW + (64 + lane) * 16);
                *(v4f*)(orow + (64 + lane) * 4) = v1;
            }
        }
    }
}

extern "C" void kernel_launch(void* const* d_in, const int* in_sizes, int n_in,
                              void* d_out, int out_size, void* d_ws, size_t ws_size,
                              hipStream_t stream) {
    const float* x  = (const float*)d_in[0];
    const float* w  = (const float*)d_in[1];
    const float* ax = (const float*)d_in[2];
    const float* aw = (const float*)d_in[3];
    float* out = (float*)d_out;

    signed char* cx = (signed char*)d_ws;   // 32*3364*64 = 6,889,472 B (padded NHWC)
    signed char* wt = cx + 6889472;         // 9*128*64   =    73,728 B  [tap][o][c]

    quant_kernel<<<1970, 256, 0, stream>>>(x, w, ax, aw, cx, wt);
    conv_kernel<<<896, 256, 0, stream>>>(cx, wt, ax, aw, out);
}

// Round 22
// 29.184 us; speedup vs baseline: 1.3562x; 1.0998x over previous
//
#include <hip/hip_runtime.h>
#include <hip/hip_bf16.h>

typedef int   v4i __attribute__((ext_vector_type(4)));
typedef float v4f __attribute__((ext_vector_type(4)));

#define HWSZ 3136   // 56*56
#define IMW  56
#define PADW 58     // 56+2 halo
#define PHW  3364   // 58*58
#define CIN  64
#define COUT 128

__device__ __forceinline__ float step_size(float a) {
    a = a > 0.f ? a : 0.f;              // relu(alpha)
    return 2.0f * a / 254.0f;
}

__device__ __forceinline__ int quant1(float x, float s) {
    float v = rintf(x / s);             // round-half-even like jnp.round
    v = fminf(127.f, fmaxf(-127.f, v)); // clip(-127, 127)
    return (int)v;
}

__device__ __forceinline__ unsigned int pack4(int a, int b, int c, int d) {
    return (unsigned int)(a & 255) | ((unsigned int)(b & 255) << 8) |
           ((unsigned int)(c & 255) << 16) | ((unsigned int)(d & 255) << 24);
}

__device__ __forceinline__ void gload_lds16(const signed char* g, signed char* l) {
    __builtin_amdgcn_global_load_lds(
        (const __attribute__((address_space(1))) void*)g,
        (__attribute__((address_space(3))) void*)l, 16, 0, 0);
}

// ---------------- fused quantize ----------------
// blocks 0..1567   : x NCHW fp32 -> padded NHWC int8 (1 n-slice, 1 hw-tile each)
// blocks 1568..1855: w OIHW -> wt[tap][o][c]
// blocks 1856..1969: zero the 1-px halo of cx
__global__ __launch_bounds__(256) void quant_kernel(const float* __restrict__ x,
                                                    const float* __restrict__ w,
                                                    const float* __restrict__ alpha_x,
                                                    const float* __restrict__ alpha_w,
                                                    signed char* __restrict__ cx,
                                                    signed char* __restrict__ wt) {
    int t = threadIdx.x;
    int b = blockIdx.x;
    if (b >= 1568) {
        if (b >= 1856) {
            int q = (b - 1856) * 256 + t;
            int n = q / 912;
            int r = q % 912;
            int px = r >> 2, seg = r & 3;
            int ph, pw;
            if (px < 58)       { ph = 0;  pw = px; }
            else if (px < 116) { ph = 57; pw = px - 58; }
            else { int k = px - 116; ph = 1 + (k >> 1); pw = (k & 1) * 57; }
            v4i z = {0, 0, 0, 0};
            *(v4i*)(cx + ((size_t)n * PHW + ph * PADW + pw) * 64 + seg * 16) = z;
            return;
        }
        float s = step_size(alpha_w[0]);
        int j = (b - 1568) * 256 + t;   // wt flat index in [tap][o][c], 73728 total
        int tap = j / 8192;
        int r   = j % 8192;
        int o   = r >> 6;
        int c   = r & 63;
        float v = w[((size_t)o * 64 + c) * 9 + tap];
        wt[j] = (signed char)quant1(v, s);
        return;
    }

    // x path: one n-slice, one 64-px tile, 64 channels
    __shared__ unsigned int tile32[64 * 17];
    float s = step_size(alpha_x[0]);
    int n   = b / 49;
    int hw0 = (b % 49) * 64;
    int g   = t & 15;
    int cq  = t >> 4;
    int p   = t >> 2;
    int seg = t & 3;

    const float* xb = x + ((size_t)n * CIN + cq * 4) * HWSZ + hw0 + g * 4;
    v4f f0 = *(const v4f*)(xb);
    v4f f1 = *(const v4f*)(xb + HWSZ);
    v4f f2 = *(const v4f*)(xb + 2 * HWSZ);
    v4f f3 = *(const v4f*)(xb + 3 * HWSZ);
#pragma unroll
    for (int j = 0; j < 4; ++j) {
        unsigned int u = pack4(quant1(f0[j], s), quant1(f1[j], s),
                               quant1(f2[j], s), quant1(f3[j], s));
        tile32[(g * 4 + j) * 17 + cq] = u;
    }
    __syncthreads();
    int base = p * 17 + seg * 4;
    v4i val;
    val[0] = (int)tile32[base + 0];
    val[1] = (int)tile32[base + 1];
    val[2] = (int)tile32[base + 2];
    val[3] = (int)tile32[base + 3];
    int hw = hw0 + p;
    int h = hw / IMW, wq = hw % IMW;
    *(v4i*)(cx + ((size_t)n * PHW + (h + 1) * PADW + (wq + 1)) * 64 + seg * 16) = val;
}

// ---------------- conv: best-known configuration (R18) ----------------
// block = 256 thr = 4 waves (o-quarters), tile = 64 px x 128 o, grid 1568.
// A window (5 padded rows) in LDS via global_load_lds; B pinned in 72 VGPR;
// zero-VMEM tap loop; LDS-transpose full-line store epilogue; 4 blocks/CU.
__global__ __launch_bounds__(256, 4) void conv_kernel(const signed char* __restrict__ cx,
                                                      const signed char* __restrict__ wt,
                                                      const float* __restrict__ ax,
                                                      const float* __restrict__ aw,
                                                      float* __restrict__ out) {
    __shared__ __attribute__((aligned(16))) signed char as_[34816];
    float scale = step_size(ax[0]) * step_size(aw[0]);
    int tid  = threadIdx.x;
    int lane = tid & 63;
    int wid  = tid >> 6;    // 0..3: o-quarter
    int row  = lane & 15;
    int kg   = lane >> 4;

    int bid  = blockIdx.x;
    int swz  = (bid & 7) * 196 + (bid >> 3);
    int p0   = swz * 64;
    int n    = p0 / HWSZ;
    int hw0  = p0 % HWSZ;
    int h0   = hw0 / IMW;
    int us   = h0 - 1; if (us > 52) us = 52;

    const signed char* wsrc = cx + ((size_t)n * PHW + (size_t)(us + 1) * PADW) * 64;
#pragma unroll
    for (int r = 0; r < 5; ++r) {
        int slotbase = r * 256 + wid * 64;
        gload_lds16(wsrc + (size_t)(slotbase + lane) * 16, as_ + slotbase * 16);
    }

    int obase = wid * 32;
    const signed char* wb = wt + (obase + row) * 64 + kg * 16;
    v4i breg[9][2];
#pragma unroll
    for (int tap = 0; tap < 9; ++tap)
#pragma unroll
        for (int ot = 0; ot < 2; ++ot)
            breg[tap][ot] = *(const v4i*)(wb + tap * (COUT * 64) + ot * (16 * 64));

    int lbase[4];
#pragma unroll
    for (int pt = 0; pt < 4; ++pt) {
        int hwp = hw0 + pt * 16 + row;
        int hh  = hwp / IMW, ww = hwp % IMW;
        lbase[pt] = ((hh - us) * PADW + (ww + 1)) * 64 + kg * 16;
    }

    asm volatile("s_waitcnt vmcnt(0)" ::: "memory");
    __syncthreads();
#pragma unroll
    for (int tap = 0; tap < 9; ++tap)
#pragma unroll
        for (int ot = 0; ot < 2; ++ot)
            asm volatile("" :: "v"(breg[tap][ot]));

    v4i acc[4][2] = {};
#pragma unroll
    for (int tap = 0; tap < 9; ++tap) {
        int doff = ((tap / 3 - 1) * PADW + (tap % 3 - 1)) * 64;
        v4i a[4];
#pragma unroll
        for (int pt = 0; pt < 4; ++pt)
            a[pt] = *(const v4i*)(as_ + lbase[pt] + doff);
#pragma unroll
        for (int pt = 0; pt < 4; ++pt)
#pragma unroll
            for (int ot = 0; ot < 2; ++ot)
                acc[pt][ot] = __builtin_amdgcn_mfma_i32_16x16x64_i8(a[pt], breg[tap][ot], acc[pt][ot], 0, 0, 0);
    }

    __syncthreads();
    signed char* scrw = as_ + wid * 8704;
    float* obb = out + ((size_t)n * COUT) * HWSZ + hw0;

#pragma unroll
    for (int otl = 0; otl < 2; ++otl) {
        int ol = otl * 16 + row;
#pragma unroll
        for (int pt = 0; pt < 4; ++pt) {
            int c  = pt * 4 + kg;
            int cs = c ^ (ol & 7);
            v4f v;
            v[0] = scale * (float)acc[pt][otl][0];
            v[1] = scale * (float)acc[pt][otl][1];
            v[2] = scale * (float)acc[pt][otl][2];
            v[3] = scale * (float)acc[pt][otl][3];
            *(v4f*)(scrw + ol * 272 + cs * 16) = v;
        }
    }
    {
        int og = lane >> 4;
        int c  = lane & 15;
#pragma unroll
        for (int j = 0; j < 8; ++j) {
            int ol = j * 4 + og;
            int cs = c ^ (ol & 7);
            v4f v = *(const v4f*)(scrw + ol * 272 + cs * 16);
            int o = obase + ol;
            *(v4f*)(obb + (size_t)o * HWSZ + c * 4) = v;
        }
    }
}

extern "C" void kernel_launch(void* const* d_in, const int* in_sizes, int n_in,
                              void* d_out, int out_size, void* d_ws, size_t ws_size,
                              hipStream_t stream) {
    const float* x  = (const float*)d_in[0];
    const float* w  = (const float*)d_in[1];
    const float* ax = (const float*)d_in[2];
    const float* aw = (const float*)d_in[3];
    float* out = (float*)d_out;

    signed char* cx = (signed char*)d_ws;   // 32*3364*64 = 6,889,472 B (padded NHWC)
    signed char* wt = cx + 6889472;         // 9*128*64   =    73,728 B  [tap][o][c]

    quant_kernel<<<1970, 256, 0, stream>>>(x, w, ax, aw, cx, wt);
    conv_kernel<<<1568, 256, 0, stream>>>(cx, wt, ax, aw, out);
}

// Round 23
// 28.745 us; speedup vs baseline: 1.3769x; 1.0153x over previous
//
#include <hip/hip_runtime.h>
#include <hip/hip_bf16.h>

typedef int   v4i __attribute__((ext_vector_type(4)));
typedef float v4f __attribute__((ext_vector_type(4)));

#define HWSZ 3136   // 56*56
#define IMW  56
#define PADW 58     // 56+2 halo
#define PHW  3364   // 58*58
#define CIN  64
#define COUT 128

__device__ __forceinline__ float step_size(float a) {
    a = a > 0.f ? a : 0.f;              // relu(alpha)
    return 2.0f * a / 254.0f;
}

__device__ __forceinline__ int quant1(float x, float s) {
    float v = rintf(x / s);             // round-half-even like jnp.round
    v = fminf(127.f, fmaxf(-127.f, v)); // clip(-127, 127)
    return (int)v;
}

__device__ __forceinline__ unsigned int pack4(int a, int b, int c, int d) {
    return (unsigned int)(a & 255) | ((unsigned int)(b & 255) << 8) |
           ((unsigned int)(c & 255) << 16) | ((unsigned int)(d & 255) << 24);
}

__device__ __forceinline__ void gload_lds16(const signed char* g, signed char* l) {
    __builtin_amdgcn_global_load_lds(
        (const __attribute__((address_space(1))) void*)g,
        (__attribute__((address_space(3))) void*)l, 16, 0, 0);
}

// ---------------- fused quantize (UNCHANGED from R22) ----------------
__global__ __launch_bounds__(256) void quant_kernel(const float* __restrict__ x,
                                                    const float* __restrict__ w,
                                                    const float* __restrict__ alpha_x,
                                                    const float* __restrict__ alpha_w,
                                                    signed char* __restrict__ cx,
                                                    signed char* __restrict__ wt) {
    int t = threadIdx.x;
    int b = blockIdx.x;
    if (b >= 1568) {
        if (b >= 1856) {
            int q = (b - 1856) * 256 + t;
            int n = q / 912;
            int r = q % 912;
            int px = r >> 2, seg = r & 3;
            int ph, pw;
            if (px < 58)       { ph = 0;  pw = px; }
            else if (px < 116) { ph = 57; pw = px - 58; }
            else { int k = px - 116; ph = 1 + (k >> 1); pw = (k & 1) * 57; }
            v4i z = {0, 0, 0, 0};
            *(v4i*)(cx + ((size_t)n * PHW + ph * PADW + pw) * 64 + seg * 16) = z;
            return;
        }
        float s = step_size(alpha_w[0]);
        int j = (b - 1568) * 256 + t;   // wt flat index in [tap][o][c], 73728 total
        int tap = j / 8192;
        int r   = j % 8192;
        int o   = r >> 6;
        int c   = r & 63;
        float v = w[((size_t)o * 64 + c) * 9 + tap];
        wt[j] = (signed char)quant1(v, s);
        return;
    }

    // x path: one n-slice, one 64-px tile, 64 channels
    __shared__ unsigned int tile32[64 * 17];
    float s = step_size(alpha_x[0]);
    int n   = b / 49;
    int hw0 = (b % 49) * 64;
    int g   = t & 15;
    int cq  = t >> 4;
    int p   = t >> 2;
    int seg = t & 3;

    const float* xb = x + ((size_t)n * CIN + cq * 4) * HWSZ + hw0 + g * 4;
    v4f f0 = *(const v4f*)(xb);
    v4f f1 = *(const v4f*)(xb + HWSZ);
    v4f f2 = *(const v4f*)(xb + 2 * HWSZ);
    v4f f3 = *(const v4f*)(xb + 3 * HWSZ);
#pragma unroll
    for (int j = 0; j < 4; ++j) {
        unsigned int u = pack4(quant1(f0[j], s), quant1(f1[j], s),
                               quant1(f2[j], s), quant1(f3[j], s));
        tile32[(g * 4 + j) * 17 + cq] = u;
    }
    __syncthreads();
    int base = p * 17 + seg * 4;
    v4i val;
    val[0] = (int)tile32[base + 0];
    val[1] = (int)tile32[base + 1];
    val[2] = (int)tile32[base + 2];
    val[3] = (int)tile32[base + 3];
    int hw = hw0 + p;
    int h = hw / IMW, wq = hw % IMW;
    *(v4i*)(cx + ((size_t)n * PHW + (h + 1) * PADW + (wq + 1)) * 64 + seg * 16) = val;
}

// ---------------- conv: R22 + nontemporal full-line stores ----------------
// Single change vs R22: epilogue global stores are nontemporal (out is never
// re-read; full 128B-line writes stream past L2, keeping cx/wt resident).
__global__ __launch_bounds__(256, 4) void conv_kernel(const signed char* __restrict__ cx,
                                                      const signed char* __restrict__ wt,
                                                      const float* __restrict__ ax,
                                                      const float* __restrict__ aw,
                                                      float* __restrict__ out) {
    __shared__ __attribute__((aligned(16))) signed char as_[34816];
    float scale = step_size(ax[0]) * step_size(aw[0]);
    int tid  = threadIdx.x;
    int lane = tid & 63;
    int wid  = tid >> 6;    // 0..3: o-quarter
    int row  = lane & 15;
    int kg   = lane >> 4;

    int bid  = blockIdx.x;
    int swz  = (bid & 7) * 196 + (bid >> 3);
    int p0   = swz * 64;
    int n    = p0 / HWSZ;
    int hw0  = p0 % HWSZ;
    int h0   = hw0 / IMW;
    int us   = h0 - 1; if (us > 52) us = 52;

    const signed char* wsrc = cx + ((size_t)n * PHW + (size_t)(us + 1) * PADW) * 64;
#pragma unroll
    for (int r = 0; r < 5; ++r) {
        int slotbase = r * 256 + wid * 64;
        gload_lds16(wsrc + (size_t)(slotbase + lane) * 16, as_ + slotbase * 16);
    }

    int obase = wid * 32;
    const signed char* wb = wt + (obase + row) * 64 + kg * 16;
    v4i breg[9][2];
#pragma unroll
    for (int tap = 0; tap < 9; ++tap)
#pragma unroll
        for (int ot = 0; ot < 2; ++ot)
            breg[tap][ot] = *(const v4i*)(wb + tap * (COUT * 64) + ot * (16 * 64));

    int lbase[4];
#pragma unroll
    for (int pt = 0; pt < 4; ++pt) {
        int hwp = hw0 + pt * 16 + row;
        int hh  = hwp / IMW, ww = hwp % IMW;
        lbase[pt] = ((hh - us) * PADW + (ww + 1)) * 64 + kg * 16;
    }

    asm volatile("s_waitcnt vmcnt(0)" ::: "memory");
    __syncthreads();
#pragma unroll
    for (int tap = 0; tap < 9; ++tap)
#pragma unroll
        for (int ot = 0; ot < 2; ++ot)
            asm volatile("" :: "v"(breg[tap][ot]));

    v4i acc[4][2] = {};
#pragma unroll
    for (int tap = 0; tap < 9; ++tap) {
        int doff = ((tap / 3 - 1) * PADW + (tap % 3 - 1)) * 64;
        v4i a[4];
#pragma unroll
        for (int pt = 0; pt < 4; ++pt)
            a[pt] = *(const v4i*)(as_ + lbase[pt] + doff);
#pragma unroll
        for (int pt = 0; pt < 4; ++pt)
#pragma unroll
            for (int ot = 0; ot < 2; ++ot)
                acc[pt][ot] = __builtin_amdgcn_mfma_i32_16x16x64_i8(a[pt], breg[tap][ot], acc[pt][ot], 0, 0, 0);
    }

    __syncthreads();
    signed char* scrw = as_ + wid * 8704;
    float* obb = out + ((size_t)n * COUT) * HWSZ + hw0;

#pragma unroll
    for (int otl = 0; otl < 2; ++otl) {
        int ol = otl * 16 + row;
#pragma unroll
        for (int pt = 0; pt < 4; ++pt) {
            int c  = pt * 4 + kg;
            int cs = c ^ (ol & 7);
            v4f v;
            v[0] = scale * (float)acc[pt][otl][0];
            v[1] = scale * (float)acc[pt][otl][1];
            v[2] = scale * (float)acc[pt][otl][2];
            v[3] = scale * (float)acc[pt][otl][3];
            *(v4f*)(scrw + ol * 272 + cs * 16) = v;
        }
    }
    {
        int og = lane >> 4;
        int c  = lane & 15;
#pragma unroll
        for (int j = 0; j < 8; ++j) {
            int ol = j * 4 + og;
            int cs = c ^ (ol & 7);
            v4f v = *(const v4f*)(scrw + ol * 272 + cs * 16);
            int o = obase + ol;
            __builtin_nontemporal_store(v, (v4f*)(obb + (size_t)o * HWSZ + c * 4));
        }
    }
}

extern "C" void kernel_launch(void* const* d_in, const int* in_sizes, int n_in,
                              void* d_out, int out_size, void* d_ws, size_t ws_size,
                              hipStream_t stream) {
    const float* x  = (const float*)d_in[0];
    const float* w  = (const float*)d_in[1];
    const float* ax = (const float*)d_in[2];
    const float* aw = (const float*)d_in[3];
    float* out = (float*)d_out;

    signed char* cx = (signed char*)d_ws;   // 32*3364*64 = 6,889,472 B (padded NHWC)
    signed char* wt = cx + 6889472;         // 9*128*64   =    73,728 B  [tap][o][c]

    quant_kernel<<<1970, 256, 0, stream>>>(x, w, ax, aw, cx, wt);
    conv_kernel<<<1568, 256, 0, stream>>>(cx, wt, ax, aw, out);
}